// Round 4
// baseline (386.011 us; speedup 1.0000x reference)
//
#include <hip/hip_runtime.h>
#include <stdint.h>

typedef unsigned short u16;
typedef unsigned int   u32;
typedef __attribute__((ext_vector_type(8))) short short8;
typedef __attribute__((ext_vector_type(4))) float f32x4;

#define S_LEN 2048
#define NEMB  2048
#define NH    16
#define NKV   4
#define HD    128
#define BATCH 2
#define MROWS (BATCH*S_LEN)   // 4096

__device__ __forceinline__ u16 f2bf(float f){
  u32 u = __float_as_uint(f);
  u += 0x7fffu + ((u>>16)&1u);
  return (u16)(u>>16);
}
__device__ __forceinline__ float bf2f(u16 h){
  return __uint_as_float(((u32)h)<<16);
}

typedef __attribute__((address_space(1))) const void gc_void;
typedef __attribute__((address_space(3))) void lds_void;
__device__ __forceinline__ void load_lds16(const void* g, void* l){
  __builtin_amdgcn_global_load_lds((gc_void*)(uintptr_t)g,
      (lds_void*)(u32)(uintptr_t)l, 16, 0, 0);
}

// ---------------- convert f32 -> bf16 (x, Wq|Wk|Wv concat, Wo) ----------------
__global__ __launch_bounds__(256) void convert_kernel(
    const float* __restrict__ x, const float* __restrict__ wq,
    const float* __restrict__ wk, const float* __restrict__ wv,
    const float* __restrict__ wo,
    u16* __restrict__ xb, u16* __restrict__ wcb, u16* __restrict__ wob){
  const size_t NX=2097152, NWQ=1048576, NWK=262144, NWV=262144, NWO=1048576;
  const size_t total = NX+NWQ+NWK+NWV+NWO;   // in float4 chunks
  for (size_t i = (size_t)blockIdx.x*blockDim.x + threadIdx.x; i < total;
       i += (size_t)gridDim.x*blockDim.x){
    const float* src; u16* dst; size_t j = i;
    if (j < NX){ src=x; dst=xb; }
    else { j-=NX;
      if (j<NWQ){ src=wq; dst=wcb; }
      else { j-=NWQ;
        if (j<NWK){ src=wk; dst=wcb+4194304; }
        else { j-=NWK;
          if (j<NWV){ src=wv; dst=wcb+5242880; }
          else { j-=NWV; src=wo; dst=wob; } } } }
    float4 v = *(const float4*)(src + j*4);
    u32 lo = (u32)f2bf(v.x) | ((u32)f2bf(v.y)<<16);
    u32 hi = (u32)f2bf(v.z) | ((u32)f2bf(v.w)<<16);
    uint2 pk; pk.x = lo; pk.y = hi;
    *(uint2*)(dst + j*4) = pk;
  }
}

// ---------------- RoPE cos/sin table: tab[(s*64+i)*2] = {cos, sin} ----------------
__global__ __launch_bounds__(256) void rope_table_kernel(const int* __restrict__ pos,
                                                         float* __restrict__ tab){
  int id = blockIdx.x*256 + threadIdx.x;
  if (id >= S_LEN*64) return;
  int s = id >> 6, i = id & 63;
  float p = (float)pos[s];
  float inv = __expf(-((float)(2*i)) * (1.0f/128.0f) * 9.210340371976184f);
  float f = p * inv;
  float sv, cv;
  sincosf(f, &sv, &cv);
  tab[id*2]   = cv;
  tab[id*2+1] = sv;
}

// ---------------- RoPE apply (interleaved pairs), optional scale ----------------
__global__ __launch_bounds__(256) void rope_apply_kernel(u16* __restrict__ buf,
    const float* __restrict__ tab, int cols, int cshift, float scale){
  int nch = MROWS * (cols>>3);
  int stride = gridDim.x*blockDim.x;
  for (int ch = blockIdx.x*blockDim.x + threadIdx.x; ch < nch; ch += stride){
    int m   = ch >> cshift;
    int cc  = ch & ((1<<cshift)-1);
    int col = cc<<3;
    int d   = col & (HD-1);
    int i0  = d >> 1;
    int s   = m & (S_LEN-1);
    const float* tp = tab + (size_t)(s*64 + i0)*2;
    float4 t0 = *(const float4*)tp;
    float4 t1 = *(const float4*)(tp+4);
    u16* bp = buf + (size_t)m*cols + col;
    union { uint4 v; u16 e[8]; } U, O;
    U.v = *(const uint4*)bp;
    float a, b;
    a=bf2f(U.e[0]); b=bf2f(U.e[1]);
    O.e[0]=f2bf((a*t0.x - b*t0.y)*scale); O.e[1]=f2bf((b*t0.x + a*t0.y)*scale);
    a=bf2f(U.e[2]); b=bf2f(U.e[3]);
    O.e[2]=f2bf((a*t0.z - b*t0.w)*scale); O.e[3]=f2bf((b*t0.z + a*t0.w)*scale);
    a=bf2f(U.e[4]); b=bf2f(U.e[5]);
    O.e[4]=f2bf((a*t1.x - b*t1.y)*scale); O.e[5]=f2bf((b*t1.x + a*t1.y)*scale);
    a=bf2f(U.e[6]); b=bf2f(U.e[7]);
    O.e[6]=f2bf((a*t1.z - b*t1.w)*scale); O.e[7]=f2bf((b*t1.z + a*t1.w)*scale);
    *(uint4*)bp = O.v;
  }
}

// ---------------- V transpose: vb [4096][512] -> vt [512][4096] ----------------
__global__ __launch_bounds__(256) void transpose_v_kernel(const u16* __restrict__ vb,
                                                          u16* __restrict__ vt){
  __shared__ u16 tl[64][72];
  int bx = blockIdx.x;
  int m0 = (bx & 63)*64;
  int d0 = (bx >> 6)*64;
  int tid = threadIdx.x;
  #pragma unroll
  for (int i=0;i<2;i++){
    int t16 = i*256 + tid;
    int sl = t16 >> 3, dc = t16 & 7;
    *(uint4*)&tl[sl][dc*8] = *(const uint4*)&vb[(size_t)(m0+sl)*512 + d0 + dc*8];
  }
  __syncthreads();
  #pragma unroll
  for (int i=0;i<2;i++){
    int t16 = i*256 + tid;
    int sch = t16 >> 6, dl = t16 & 63;
    union { uint4 v; u16 e[8]; } O;
    #pragma unroll
    for (int j=0;j<8;j++) O.e[j] = tl[sch*8+j][dl];
    *(uint4*)&vt[(size_t)(d0+dl)*4096 + m0 + sch*8] = O.v;
  }
}

// ================= 256x256 8-phase bf16 GEMM (T2+T3+T4+T5), B^T input =================
// 8 waves (2M x 4N), BK=64, per-wave C = 128x64 = acc[8][4].
// LDS 128 KiB: A[2buf][2unit][1024 slot16], B likewise at +64 KiB.
// Stage units grouped by first-use phase: SA0,SB0,SB1,SA1 (queue order fixed).
// EPI 0: scatter bf16 to Q/K/V (N=3072). EPI 1: f32 out (N=2048).
template<int EPI>
__global__ __launch_bounds__(512,1) void gemm256_kernel(
    const u16* __restrict__ A, const u16* __restrict__ B, int K, int ntx,
    u16* __restrict__ q_out, u16* __restrict__ k_out, u16* __restrict__ v_out,
    float* __restrict__ f_out){
  __shared__ char ldsb[131072];
  int tid = threadIdx.x;
  int lane = tid & 63;
  int wid  = tid >> 6;
  int lr = lane & 15, lc = lane >> 4;
  int wm2 = wid >> 2;          // 0..1  -> m offset wm2*128
  int wn4 = wid & 3;           // 0..3  -> n offset wn4*64

  // bijective XCD swizzle (nwg % 8 == 0 for both call sites)
  int nwg = ntx * 16;
  int bid = blockIdx.x;
  int wg = (bid & 7)*(nwg >> 3) + (bid >> 3);
  int by = wg / ntx, bx = wg % ntx;
  int bm = by*256, bn = bx*256;

  const u16* Ag = A + (size_t)bm*K;
  const u16* Bg = B + (size_t)bn*K;

  // ---- staging: one unit = 16 KiB = 2 x load_lds16 per thread ----
  auto stageA = [&](int p, int kt, int h){
    const u16* src = Ag + (size_t)kt*64;
    char* dstb = ldsb + p*32768 + h*16384 + (size_t)(tid & 448)*16;
    #pragma unroll
    for (int i=0;i<2;i++){
      int S = i*512 + tid;
      int rr = S >> 3;
      int r  = ((rr>>6)<<7) | (h<<6) | (rr & 63);
      int c8 = (S & 7) ^ (rr & 7);
      load_lds16(src + (size_t)r*K + c8*8, dstb + i*8192);
    }
  };
  auto stageB = [&](int p, int kt, int h){
    const u16* src = Bg + (size_t)kt*64;
    char* dstb = ldsb + 65536 + p*32768 + h*16384 + (size_t)(tid & 448)*16;
    #pragma unroll
    for (int i=0;i<2;i++){
      int S = i*512 + tid;
      int rr = S >> 3;
      int n  = ((rr>>5)<<6) | (h<<5) | (rr & 31);
      int c8 = (S & 7) ^ (rr & 7);
      load_lds16(src + (size_t)n*K + c8*8, dstb + i*8192);
    }
  };

  f32x4 acc[8][4];
  #pragma unroll
  for (int i=0;i<8;i++)
    #pragma unroll
    for (int j=0;j<4;j++) acc[i][j] = (f32x4)0.0f;

  short8 a[4][2], b0[2][2], b1[2][2];
  int xorv = (lr & 7) << 4;

  // read helpers (compile-time mh/nh/mf/nf/kk via unrolled loops)
  #define RD_A(mh, mf, kk, p) \
    (*(const short8*)(ldsb + (p)*32768 + (mh)*16384 + wm2*8192 + \
      ((((mf)*16 + lr)*128 + (kk)*64 + lc*16) ^ xorv)))
  #define RD_B(nh, nf, kk, p) \
    (*(const short8*)(ldsb + 65536 + (p)*32768 + (nh)*16384 + wn4*4096 + \
      ((((nf)*16 + lr)*128 + (kk)*64 + lc*16) ^ xorv)))

  int nk = K >> 6;   // 32

  // ---- prologue: stage tile 0 (order SA0,SB0,SB1,SA1), wait first two units ----
  stageA(0, 0, 0);
  stageB(0, 0, 0);
  stageB(0, 0, 1);
  stageA(0, 0, 1);
  asm volatile("s_waitcnt vmcnt(4)" ::: "memory");
  __builtin_amdgcn_s_barrier();

  for (int t = 0; t < nk; ++t){
    int p = t & 1;
    bool doStage = (t+1 < nk);

    // ===== phase 0: quad(0,0) =====
    #pragma unroll
    for (int mf=0; mf<4; mf++){
      a[mf][0] = RD_A(0, mf, 0, p);
      a[mf][1] = RD_A(0, mf, 1, p);
    }
    #pragma unroll
    for (int nf=0; nf<2; nf++){
      b0[nf][0] = RD_B(0, nf, 0, p);
      b0[nf][1] = RD_B(0, nf, 1, p);
    }
    if (doStage) stageA(p^1, t+1, 0);
    __builtin_amdgcn_s_barrier();
    __builtin_amdgcn_s_setprio(1);
    #pragma unroll
    for (int kk=0; kk<2; kk++)
      #pragma unroll
      for (int mf=0; mf<4; mf++)
        #pragma unroll
        for (int nf=0; nf<2; nf++)
          acc[mf][nf] = __builtin_amdgcn_mfma_f32_16x16x32_bf16(a[mf][kk], b0[nf][kk], acc[mf][nf], 0,0,0);
    __builtin_amdgcn_s_setprio(0);
    if (doStage) { asm volatile("s_waitcnt vmcnt(4)" ::: "memory"); }
    else         { asm volatile("s_waitcnt vmcnt(2)" ::: "memory"); }
    __builtin_amdgcn_s_barrier();

    // ===== phase 1: quad(0,1) =====
    #pragma unroll
    for (int nf=0; nf<2; nf++){
      b1[nf][0] = RD_B(1, nf, 0, p);
      b1[nf][1] = RD_B(1, nf, 1, p);
    }
    if (doStage) stageB(p^1, t+1, 0);
    __builtin_amdgcn_s_barrier();
    __builtin_amdgcn_s_setprio(1);
    #pragma unroll
    for (int kk=0; kk<2; kk++)
      #pragma unroll
      for (int mf=0; mf<4; mf++)
        #pragma unroll
        for (int nf=0; nf<2; nf++)
          acc[mf][2+nf] = __builtin_amdgcn_mfma_f32_16x16x32_bf16(a[mf][kk], b1[nf][kk], acc[mf][2+nf], 0,0,0);
    __builtin_amdgcn_s_setprio(0);
    if (doStage) { asm volatile("s_waitcnt vmcnt(4)" ::: "memory"); }
    else         { asm volatile("s_waitcnt vmcnt(0)" ::: "memory"); }
    __builtin_amdgcn_s_barrier();

    // ===== phase 2: quad(1,0) =====
    #pragma unroll
    for (int mf=0; mf<4; mf++){
      a[mf][0] = RD_A(1, mf, 0, p);
      a[mf][1] = RD_A(1, mf, 1, p);
    }
    if (doStage) stageB(p^1, t+1, 1);
    __builtin_amdgcn_s_barrier();
    __builtin_amdgcn_s_setprio(1);
    #pragma unroll
    for (int kk=0; kk<2; kk++)
      #pragma unroll
      for (int mf=0; mf<4; mf++)
        #pragma unroll
        for (int nf=0; nf<2; nf++)
          acc[4+mf][nf] = __builtin_amdgcn_mfma_f32_16x16x32_bf16(a[mf][kk], b0[nf][kk], acc[4+mf][nf], 0,0,0);
    __builtin_amdgcn_s_setprio(0);
    __builtin_amdgcn_s_barrier();

    // ===== phase 3: quad(1,1) =====
    if (doStage) stageA(p^1, t+1, 1);
    __builtin_amdgcn_s_barrier();
    __builtin_amdgcn_s_setprio(1);
    #pragma unroll
    for (int kk=0; kk<2; kk++)
      #pragma unroll
      for (int mf=0; mf<4; mf++)
        #pragma unroll
        for (int nf=0; nf<2; nf++)
          acc[4+mf][2+nf] = __builtin_amdgcn_mfma_f32_16x16x32_bf16(a[mf][kk], b1[nf][kk], acc[4+mf][2+nf], 0,0,0);
    __builtin_amdgcn_s_setprio(0);
    if (doStage) { asm volatile("s_waitcnt vmcnt(4)" ::: "memory"); }
    __builtin_amdgcn_s_barrier();
  }
  #undef RD_A
  #undef RD_B

  // ---- epilogue ----
  #pragma unroll
  for (int mfi=0; mfi<8; mfi++){
    #pragma unroll
    for (int nfi=0; nfi<4; nfi++){
      #pragma unroll
      for (int r=0; r<4; r++){
        int m = bm + wm2*128 + mfi*16 + lc*4 + r;
        int n = bn + wn4*64 + nfi*16 + lr;
        float v = acc[mfi][nfi][r];
        if (EPI == 0){
          if (n < 2048)      q_out[(size_t)m*2048 + n]        = f2bf(v);
          else if (n < 2560) k_out[(size_t)m*512 + (n-2048)]  = f2bf(v);
          else               v_out[(size_t)m*512 + (n-2560)]  = f2bf(v);
        } else {
          f_out[(size_t)m*2048 + n] = v;
        }
      }
    }
  }
}

// ---------------- flash attention v2: KVBLK=64, pure global_load_lds staging ----------------
__global__ __launch_bounds__(256,2) void attn_kernel(
    const u16* __restrict__ Q, const u16* __restrict__ Kb,
    const u16* __restrict__ Vt, u16* __restrict__ Y){
  __shared__ u16 sK[2][64*128];    // [kv][128d], XOR-swizzled 16B chunks
  __shared__ u16 sVt[2][128*64];   // [d][64kv], XOR-swizzled 16B chunks
  __shared__ u16 sP[4][16*64];     // per-wave P, XOR-swizzled

  int tid = threadIdx.x, wave = tid>>6, lane = tid&63;
  int lr = lane&15, lc = lane>>4;

  int bid = blockIdx.x;
  int kvg  = bid & 7;          // (b,hk) — XCD-sticky under %8 round-robin
  int rest = bid >> 3;
  int qtr  = rest & 31;
  int hsub = rest >> 5;        // 0..3
  int qt = 31 - qtr;           // longest first
  int b  = kvg >> 2;
  int hk = kvg & 3;
  int h  = hk*4 + hsub;

  int q0  = qt*64;
  int qrb = q0 + wave*16;
  const u16* Qg = Q  + (size_t)(b*S_LEN + qrb)*NEMB + h*HD;
  const u16* Kg = Kb + (size_t)(b*S_LEN)*512 + hk*HD;
  const u16* Vg = Vt + (size_t)(hk*HD)*4096 + b*S_LEN;

  auto stage = [&](int buf, int kv0){
    #pragma unroll
    for (int i=0;i<4;i++){
      int t16 = i*256 + tid;
      int row = t16 >> 4, c = t16 & 15;
      int cgl = c ^ (row & 7);
      load_lds16(Kg + (size_t)(kv0+row)*512 + cgl*8,
                 &sK[buf][(size_t)(i*256 + (tid & 192))*8]);
    }
    #pragma unroll
    for (int i=0;i<4;i++){
      int t16 = i*256 + tid;
      int d = t16 >> 3, c = t16 & 7;
      int cgl = c ^ (d & 7);
      load_lds16(Vg + (size_t)d*4096 + kv0 + cgl*8,
                 &sVt[buf][(size_t)(i*256 + (tid & 192))*8]);
    }
  };

  short8 qf[4];
  #pragma unroll
  for (int c=0;c<4;c++)
    qf[c] = *(const short8*)&Qg[(size_t)lr*NEMB + c*32 + lc*8];

  float m_run[4], l_run[4];
  #pragma unroll
  for (int r=0;r<4;r++){ m_run[r]=-1e30f; l_run[r]=0.0f; }
  f32x4 o[8];
  #pragma unroll
  for (int i=0;i<8;i++) o[i]=(f32x4)0.0f;

  int nt = qt + 1;
  stage(0,0);
  __syncthreads();
  int cur=0;
  char* spb = (char*)sP[wave];
  for (int t=0;t<nt;++t){
    int kv0 = t*64;
    if (t+1<nt) stage(cur^1,(t+1)*64);

    // ---- QK^T ----
    f32x4 sc[4];
    #pragma unroll
    for (int c2=0;c2<4;c2++) sc[c2]=(f32x4)0.0f;
    const char* skb = (const char*)sK[cur];
    __builtin_amdgcn_s_setprio(1);
    #pragma unroll
    for (int c2=0;c2<4;c2++){
      int rr = c2*16 + lr;
      int xo = (rr&7)<<4;
      #pragma unroll
      for (int c=0;c<4;c++){
        int byteoff = (rr*256 + c*64 + lc*16) ^ xo;
        short8 kf = *(const short8*)(skb + byteoff);
        sc[c2] = __builtin_amdgcn_mfma_f32_16x16x32_bf16(qf[c], kf, sc[c2], 0,0,0);
      }
    }
    __builtin_amdgcn_s_setprio(0);

    if (t == nt-1){          // diagonal tile: causal mask
      #pragma unroll
      for (int c2=0;c2<4;c2++){
        int kvgl = kv0 + c2*16 + lr;
        #pragma unroll
        for (int r=0;r<4;r++){
          int qg = qrb + lc*4 + r;
          if (kvgl > qg) sc[c2][r] = -1e30f;
        }
      }
    }

    float fac[4];
    #pragma unroll
    for (int r=0;r<4;r++){
      float mm = fmaxf(fmaxf(sc[0][r],sc[1][r]), fmaxf(sc[2][r],sc[3][r]));
      mm = fmaxf(mm, __shfl_xor(mm,1));
      mm = fmaxf(mm, __shfl_xor(mm,2));
      mm = fmaxf(mm, __shfl_xor(mm,4));
      mm = fmaxf(mm, __shfl_xor(mm,8));
      float mn = fmaxf(m_run[r], mm);
      fac[r] = __expf(m_run[r]-mn);
      m_run[r] = mn;
      float p0 = __expf(sc[0][r]-mn);
      float p1 = __expf(sc[1][r]-mn);
      float p2 = __expf(sc[2][r]-mn);
      float p3 = __expf(sc[3][r]-mn);
      sc[0][r]=p0; sc[1][r]=p1; sc[2][r]=p2; sc[3][r]=p3;
      float ss = (p0+p1)+(p2+p3);
      ss += __shfl_xor(ss,1); ss += __shfl_xor(ss,2);
      ss += __shfl_xor(ss,4); ss += __shfl_xor(ss,8);
      l_run[r] = l_run[r]*fac[r] + ss;
    }
    #pragma unroll
    for (int i=0;i<8;i++)
      #pragma unroll
      for (int r=0;r<4;r++) o[i][r] *= fac[r];

    #pragma unroll
    for (int c2=0;c2<4;c2++){
      #pragma unroll
      for (int r=0;r<4;r++){
        int row = lc*4+r;
        int byteoff = (row*128 + (c2*16+lr)*2) ^ ((row&7)<<4);
        *(u16*)(spb + byteoff) = f2bf(sc[c2][r]);
      }
    }
    short8 pa[2];
    {
      int xop = (lr&7)<<4;
      pa[0] = *(const short8*)(spb + ((lr*128 + lc*16) ^ xop));
      pa[1] = *(const short8*)(spb + ((lr*128 + 64 + lc*16) ^ xop));
    }

    const char* svb = (const char*)sVt[cur];
    __builtin_amdgcn_s_setprio(1);
    #pragma unroll
    for (int n=0;n<8;n++){
      int d = n*16+lr;
      int xo = (d&7)<<4;
      #pragma unroll
      for (int ks=0;ks<2;ks++){
        int byteoff = (d*128 + ks*64 + lc*16) ^ xo;
        short8 vf = *(const short8*)(svb + byteoff);
        o[n] = __builtin_amdgcn_mfma_f32_16x16x32_bf16(pa[ks], vf, o[n], 0,0,0);
      }
    }
    __builtin_amdgcn_s_setprio(0);

    __syncthreads();
    cur ^= 1;
  }

  u16* Yg = Y + (size_t)(b*S_LEN + qrb)*NEMB + h*HD;
  #pragma unroll
  for (int n=0;n<8;n++){
    #pragma unroll
    for (int r=0;r<4;r++){
      float v = o[n][r] / l_run[r];
      Yg[(size_t)(lc*4+r)*NEMB + n*16 + lr] = f2bf(v);
    }
  }
}

// ---------------- launch ----------------
extern "C" void kernel_launch(void* const* d_in, const int* in_sizes, int n_in,
                              void* d_out, int out_size, void* d_ws, size_t ws_size,
                              hipStream_t stream){
  const float* x  = (const float*)d_in[0];
  const float* wq = (const float*)d_in[1];
  const float* wk = (const float*)d_in[2];
  const float* wv = (const float*)d_in[3];
  const float* wo = (const float*)d_in[4];
  const int*  pos = (const int*)d_in[5];
  float* out = (float*)d_out;

  char* ws = (char*)d_ws;
  size_t off = 0;
  auto alloc = [&](size_t bytes)->char*{
    char* p = ws + off; off += (bytes + 255) & ~(size_t)255; return p;
  };
  u16* xb  = (u16*)alloc(8388608ull*2);   // x bf16 (4096x2048); reused as vt after gemm<0>
  u16* wcb = (u16*)alloc(6291456ull*2);   // Wq|Wk|Wv bf16 (3072x2048)
  u16* wob = (u16*)alloc(4194304ull*2);   // Wo bf16 (2048x2048)
  u16* qb  = (u16*)alloc(8388608ull*2);   // Q (4096x2048)
  u16* kb  = (u16*)alloc(2097152ull*2);   // K (4096x512)
  u16* vb  = (u16*)alloc(2097152ull*2);   // V (4096x512)
  u16* yb  = (u16*)alloc(8388608ull*2);   // attn out (4096x2048)
  float* tab = (float*)alloc((size_t)S_LEN*64*2*4);
  u16* vt = xb;                           // V^T [512][4096] (4 MB) — xb dead after gemm<0>

  convert_kernel<<<2048,256,0,stream>>>(x,wq,wk,wv,wo,xb,wcb,wob);
  rope_table_kernel<<<512,256,0,stream>>>(pos, tab);
  gemm256_kernel<0><<<192,512,0,stream>>>(xb, wcb, 2048, 12, qb, kb, vb, nullptr);
  rope_apply_kernel<<<2048,256,0,stream>>>(qb, tab, 2048, 8, 0.08838834764831845f);
  rope_apply_kernel<<<1024,256,0,stream>>>(kb, tab, 512, 6, 1.0f);
  transpose_v_kernel<<<512,256,0,stream>>>(vb, vt);
  attn_kernel<<<1024,256,0,stream>>>(qb, kb, vt, yb);
  gemm256_kernel<1><<<128,512,0,stream>>>(yb, wob, 2048, 8, nullptr,nullptr,nullptr, out);
}

// Round 7
// 349.300 us; speedup vs baseline: 1.1051x; 1.1051x over previous
//
#include <hip/hip_runtime.h>
#include <stdint.h>

typedef unsigned short u16;
typedef unsigned int   u32;
typedef __attribute__((ext_vector_type(8))) short short8;
typedef __attribute__((ext_vector_type(4))) float f32x4;

#define S_LEN 2048
#define NEMB  2048
#define NH    16
#define NKV   4
#define HD    128
#define BATCH 2
#define MROWS (BATCH*S_LEN)   // 4096

// 1/sqrt(128) * log2(e): scores land in log2 domain -> bare v_exp_f32 softmax
#define SCALE_Q 0.12751744f

__device__ __forceinline__ u16 f2bf(float f){
  u32 u = __float_as_uint(f);
  u += 0x7fffu + ((u>>16)&1u);
  return (u16)(u>>16);
}
__device__ __forceinline__ float bf2f(u16 h){
  return __uint_as_float(((u32)h)<<16);
}
__device__ __forceinline__ float exp2_fast(float x){
  float r;
  asm("v_exp_f32 %0, %1" : "=v"(r) : "v"(x));
  return r;
}

typedef __attribute__((address_space(1))) const void gc_void;
typedef __attribute__((address_space(3))) void lds_void;
__device__ __forceinline__ void load_lds16(const void* g, void* l){
  __builtin_amdgcn_global_load_lds((gc_void*)(uintptr_t)g,
      (lds_void*)(u32)(uintptr_t)l, 16, 0, 0);
}

// ---------------- convert f32 -> bf16 (x, Wq|Wk|Wv concat, Wo) ----------------
__global__ __launch_bounds__(256) void convert_kernel(
    const float* __restrict__ x, const float* __restrict__ wq,
    const float* __restrict__ wk, const float* __restrict__ wv,
    const float* __restrict__ wo,
    u16* __restrict__ xb, u16* __restrict__ wcb, u16* __restrict__ wob){
  const size_t NX=2097152, NWQ=1048576, NWK=262144, NWV=262144, NWO=1048576;
  const size_t total = NX+NWQ+NWK+NWV+NWO;   // in float4 chunks
  for (size_t i = (size_t)blockIdx.x*blockDim.x + threadIdx.x; i < total;
       i += (size_t)gridDim.x*blockDim.x){
    const float* src; u16* dst; size_t j = i;
    if (j < NX){ src=x; dst=xb; }
    else { j-=NX;
      if (j<NWQ){ src=wq; dst=wcb; }
      else { j-=NWQ;
        if (j<NWK){ src=wk; dst=wcb+4194304; }
        else { j-=NWK;
          if (j<NWV){ src=wv; dst=wcb+5242880; }
          else { j-=NWV; src=wo; dst=wob; } } } }
    float4 v = *(const float4*)(src + j*4);
    u32 lo = (u32)f2bf(v.x) | ((u32)f2bf(v.y)<<16);
    u32 hi = (u32)f2bf(v.z) | ((u32)f2bf(v.w)<<16);
    uint2 pk; pk.x = lo; pk.y = hi;
    *(uint2*)(dst + j*4) = pk;
  }
}

// ---------------- RoPE cos/sin table: tab[s*64+i] = {cos, sin} ----------------
__global__ __launch_bounds__(256) void rope_table_kernel(const int* __restrict__ pos,
                                                         float2* __restrict__ tab){
  int id = blockIdx.x*256 + threadIdx.x;
  if (id >= S_LEN*64) return;
  int s = id >> 6, i = id & 63;
  float p = (float)pos[s];
  float inv = __expf(-((float)(2*i)) * (1.0f/128.0f) * 9.210340371976184f);
  float f = p * inv;
  float sv, cv;
  sincosf(f, &sv, &cv);
  tab[id] = make_float2(cv, sv);
}

// ---------------- V transpose: vb [4096][512] -> vt [512][4096] ----------------
__global__ __launch_bounds__(256) void transpose_v_kernel(const u16* __restrict__ vb,
                                                          u16* __restrict__ vt){
  __shared__ u16 tl[64][72];
  int bx = blockIdx.x;
  int m0 = (bx & 63)*64;
  int d0 = (bx >> 6)*64;
  int tid = threadIdx.x;
  #pragma unroll
  for (int i=0;i<2;i++){
    int t16 = i*256 + tid;
    int sl = t16 >> 3, dc = t16 & 7;
    *(uint4*)&tl[sl][dc*8] = *(const uint4*)&vb[(size_t)(m0+sl)*512 + d0 + dc*8];
  }
  __syncthreads();
  #pragma unroll
  for (int i=0;i<2;i++){
    int t16 = i*256 + tid;
    int sch = t16 >> 6, dl = t16 & 63;
    union { uint4 v; u16 e[8]; } O;
    #pragma unroll
    for (int j=0;j<8;j++) O.e[j] = tl[sch*8+j][dl];
    *(uint4*)&vt[(size_t)(d0+dl)*4096 + m0 + sch*8] = O.v;
  }
}

// ---------------- 128x128 bf16 GEMM, B^T input ----------------
// EPI 0: QKV proj — RoPE fused in epilogue (Q scaled by SCALE_Q), scatter to q/k/v
// EPI 1: output proj — f32 to f_out
template<int EPI>
__global__ __launch_bounds__(256,2) void gemm128_kernel(
    const u16* __restrict__ A, const u16* __restrict__ B, int K,
    const float2* __restrict__ tab,
    u16* __restrict__ q_out, u16* __restrict__ k_out, u16* __restrict__ v_out,
    float* __restrict__ f_out){
  __shared__ u16 sA[2][128*32];
  __shared__ u16 sB[2][128*32];
  int tid = threadIdx.x;
  int wave = tid >> 6, lane = tid & 63;
  int lr = lane & 15, lc = lane >> 4;
  int wm = (wave>>1)*64, wn = (wave&1)*64;
  int bm = blockIdx.y*128, bn = blockIdx.x*128;
  const u16* Ag = A + (size_t)bm*K;
  const u16* Bg = B + (size_t)bn*K;

  auto stage = [&](int buf, int kt){
    const u16* Ak = Ag + kt*32;
    const u16* Bk = Bg + kt*32;
    #pragma unroll
    for (int rrd=0; rrd<2; ++rrd){
      int t16 = rrd*256 + tid;
      int row = t16 >> 2, ch = t16 & 3;
      u16* lb = &sA[buf][(size_t)(rrd*256 + (tid & 192))*8];
      load_lds16(Ak + (size_t)row*K + ch*8, lb);
    }
    #pragma unroll
    for (int rrd=0; rrd<2; ++rrd){
      int t16 = rrd*256 + tid;
      int row = t16 >> 2, ch = t16 & 3;
      u16* lb = &sB[buf][(size_t)(rrd*256 + (tid & 192))*8];
      load_lds16(Bk + (size_t)row*K + ch*8, lb);
    }
  };

  f32x4 acc[4][4];
  #pragma unroll
  for (int i=0;i<4;i++)
    #pragma unroll
    for (int j=0;j<4;j++) acc[i][j] = (f32x4)0.0f;

  stage(0,0);
  __syncthreads();
  int nk = K >> 5;
  int cur = 0;
  for (int kt=0; kt<nk; ++kt){
    if (kt+1 < nk) stage(cur^1, kt+1);
    short8 af[4], bfr[4];
    #pragma unroll
    for (int i=0;i<4;i++){
      af[i]  = *(const short8*)&sA[cur][(wm + i*16 + lr)*32 + lc*8];
      bfr[i] = *(const short8*)&sB[cur][(wn + i*16 + lr)*32 + lc*8];
    }
    __builtin_amdgcn_s_setprio(1);
    #pragma unroll
    for (int i=0;i<4;i++)
      #pragma unroll
      for (int j=0;j<4;j++)
        acc[i][j] = __builtin_amdgcn_mfma_f32_16x16x32_bf16(af[i], bfr[j], acc[i][j], 0,0,0);
    __builtin_amdgcn_s_setprio(0);
    __syncthreads();
    cur ^= 1;
  }

  #pragma unroll
  for (int i=0;i<4;i++){
    #pragma unroll
    for (int j=0;j<4;j++){
      #pragma unroll
      for (int r=0;r<4;r++){
        int m = bm + wm + i*16 + lc*4 + r;
        int n = bn + wn + j*16 + lr;
        float v = acc[i][j][r];
        if (EPI == 0){
          // RoPE: partner value (d ^ 1) lives in lane^1 (lr parity)
          float p = __shfl_xor(v, 1);
          if (n < 2048){
            float2 cs = tab[((m & (S_LEN-1))<<6) + ((n & 127)>>1)];
            float o = (n & 1) ? (v*cs.x + p*cs.y) : (v*cs.x - p*cs.y);
            q_out[(size_t)m*2048 + n] = f2bf(o * SCALE_Q);
          } else if (n < 2560){
            int d = n - 2048;           // d in [0,512): head dim = d&127
            float2 cs = tab[((m & (S_LEN-1))<<6) + ((d & 127)>>1)];
            float o = (n & 1) ? (v*cs.x + p*cs.y) : (v*cs.x - p*cs.y);
            k_out[(size_t)m*512 + d] = f2bf(o);
          } else {
            v_out[(size_t)m*512 + (n-2560)] = f2bf(v);
          }
        } else {
          f_out[(size_t)m*2048 + n] = v;
        }
      }
    }
  }
}

// ---------------- flash attention: KVBLK=64, exp2 softmax + defer-max ----------------
// block = 64 q rows x 4 waves; decode: bid&7 = (b,hk) [XCD-sticky], longest-qt first
__global__ __launch_bounds__(256,2) void attn_kernel(
    const u16* __restrict__ Q, const u16* __restrict__ Kb,
    const u16* __restrict__ Vt, u16* __restrict__ Y){
  __shared__ u16 sK[2][64*128];    // [kv][128d], XOR-swizzled 16B chunks
  __shared__ u16 sVt[2][128*64];   // [d][64kv], XOR-swizzled 16B chunks
  __shared__ u16 sP[4][16*64];     // per-wave P, XOR-swizzled

  int tid = threadIdx.x, wave = tid>>6, lane = tid&63;
  int lr = lane&15, lc = lane>>4;

  int bid = blockIdx.x;
  int kvg  = bid & 7;
  int rest = bid >> 3;
  int qtr  = rest & 31;
  int hsub = rest >> 5;
  int qt = 31 - qtr;           // longest first
  int b  = kvg >> 2;
  int hk = kvg & 3;
  int h  = hk*4 + hsub;

  int q0  = qt*64;
  int qrb = q0 + wave*16;
  const u16* Qg = Q  + (size_t)(b*S_LEN + qrb)*NEMB + h*HD;
  const u16* Kg = Kb + (size_t)(b*S_LEN)*512 + hk*HD;
  const u16* Vg = Vt + (size_t)(hk*HD)*4096 + b*S_LEN;

  auto stage = [&](int buf, int kv0){
    #pragma unroll
    for (int i=0;i<4;i++){
      int t16 = i*256 + tid;
      int row = t16 >> 4, c = t16 & 15;
      int cgl = c ^ (row & 7);
      load_lds16(Kg + (size_t)(kv0+row)*512 + cgl*8,
                 &sK[buf][(size_t)(i*256 + (tid & 192))*8]);
    }
    #pragma unroll
    for (int i=0;i<4;i++){
      int t16 = i*256 + tid;
      int d = t16 >> 3, c = t16 & 7;
      int cgl = c ^ (d & 7);
      load_lds16(Vg + (size_t)d*4096 + kv0 + cgl*8,
                 &sVt[buf][(size_t)(i*256 + (tid & 192))*8]);
    }
  };

  short8 qf[4];
  #pragma unroll
  for (int c=0;c<4;c++)
    qf[c] = *(const short8*)&Qg[(size_t)lr*NEMB + c*32 + lc*8];

  float m_run[4], l_run[4];
  #pragma unroll
  for (int r=0;r<4;r++){ m_run[r]=-1e30f; l_run[r]=0.0f; }
  f32x4 o[8];
  #pragma unroll
  for (int i=0;i<8;i++) o[i]=(f32x4)0.0f;

  int nt = qt + 1;
  stage(0,0);
  __syncthreads();
  int cur=0;
  char* spb = (char*)sP[wave];
  for (int t=0;t<nt;++t){
    int kv0 = t*64;
    if (t+1<nt) stage(cur^1,(t+1)*64);

    // ---- QK^T (scores already in log2 units via SCALE_Q on Q) ----
    f32x4 sc[4];
    #pragma unroll
    for (int c2=0;c2<4;c2++) sc[c2]=(f32x4)0.0f;
    const char* skb = (const char*)sK[cur];
    __builtin_amdgcn_s_setprio(1);
    #pragma unroll
    for (int c2=0;c2<4;c2++){
      int rr = c2*16 + lr;
      int xo = (rr&7)<<4;
      #pragma unroll
      for (int c=0;c<4;c++){
        int byteoff = (rr*256 + c*64 + lc*16) ^ xo;
        short8 kf = *(const short8*)(skb + byteoff);
        sc[c2] = __builtin_amdgcn_mfma_f32_16x16x32_bf16(qf[c], kf, sc[c2], 0,0,0);
      }
    }
    __builtin_amdgcn_s_setprio(0);

    if (t == nt-1){          // diagonal tile: causal mask (ALL waves — R6 fix)
      #pragma unroll
      for (int c2=0;c2<4;c2++){
        int kvgl = kv0 + c2*16 + lr;
        #pragma unroll
        for (int r=0;r<4;r++){
          int qg = qrb + lc*4 + r;
          if (kvgl > qg) sc[c2][r] = -1e30f;
        }
      }
    }

    // ---- defer-max online softmax (T13): lane-local test, no shfl on skip ----
    float lmax[4];
    bool need = false;
    #pragma unroll
    for (int r=0;r<4;r++){
      lmax[r] = fmaxf(fmaxf(sc[0][r],sc[1][r]), fmaxf(sc[2][r],sc[3][r]));
      need = need || (lmax[r] > m_run[r] + 8.0f);
    }
    if (__any(need)){
      float fac[4];
      #pragma unroll
      for (int r=0;r<4;r++){
        float mm = lmax[r];
        mm = fmaxf(mm, __shfl_xor(mm,1));
        mm = fmaxf(mm, __shfl_xor(mm,2));
        mm = fmaxf(mm, __shfl_xor(mm,4));
        mm = fmaxf(mm, __shfl_xor(mm,8));
        float mn = fmaxf(m_run[r], mm);
        fac[r] = exp2_fast(m_run[r]-mn);
        m_run[r] = mn;
        l_run[r] *= fac[r];
      }
      #pragma unroll
      for (int i=0;i<8;i++)
        #pragma unroll
        for (int r=0;r<4;r++) o[i][r] *= fac[r];
    }
    #pragma unroll
    for (int r=0;r<4;r++){
      float p0 = exp2_fast(sc[0][r]-m_run[r]);
      float p1 = exp2_fast(sc[1][r]-m_run[r]);
      float p2 = exp2_fast(sc[2][r]-m_run[r]);
      float p3 = exp2_fast(sc[3][r]-m_run[r]);
      sc[0][r]=p0; sc[1][r]=p1; sc[2][r]=p2; sc[3][r]=p3;
      float ss = (p0+p1)+(p2+p3);
      ss += __shfl_xor(ss,1); ss += __shfl_xor(ss,2);
      ss += __shfl_xor(ss,4); ss += __shfl_xor(ss,8);
      l_run[r] += ss;
    }

    // ---- P: C-layout -> swizzled LDS -> A-frag ----
    #pragma unroll
    for (int c2=0;c2<4;c2++){
      #pragma unroll
      for (int r=0;r<4;r++){
        int row = lc*4+r;
        int byteoff = (row*128 + (c2*16+lr)*2) ^ ((row&7)<<4);
        *(u16*)(spb + byteoff) = f2bf(sc[c2][r]);
      }
    }
    short8 pa[2];
    {
      int xop = (lr&7)<<4;
      pa[0] = *(const short8*)(spb + ((lr*128 + lc*16) ^ xop));
      pa[1] = *(const short8*)(spb + ((lr*128 + 64 + lc*16) ^ xop));
    }

    // ---- PV ----
    const char* svb = (const char*)sVt[cur];
    __builtin_amdgcn_s_setprio(1);
    #pragma unroll
    for (int n=0;n<8;n++){
      int d = n*16+lr;
      int xo = (d&7)<<4;
      #pragma unroll
      for (int ks=0;ks<2;ks++){
        int byteoff = (d*128 + ks*64 + lc*16) ^ xo;
        short8 vf = *(const short8*)(svb + byteoff);
        o[n] = __builtin_amdgcn_mfma_f32_16x16x32_bf16(pa[ks], vf, o[n], 0,0,0);
      }
    }
    __builtin_amdgcn_s_setprio(0);

    __syncthreads();
    cur ^= 1;
  }

  u16* Yg = Y + (size_t)(b*S_LEN + qrb)*NEMB + h*HD;
  #pragma unroll
  for (int n=0;n<8;n++){
    #pragma unroll
    for (int r=0;r<4;r++){
      float v = o[n][r] / l_run[r];
      Yg[(size_t)(lc*4+r)*NEMB + n*16 + lr] = f2bf(v);
    }
  }
}

// ---------------- launch ----------------
extern "C" void kernel_launch(void* const* d_in, const int* in_sizes, int n_in,
                              void* d_out, int out_size, void* d_ws, size_t ws_size,
                              hipStream_t stream){
  const float* x  = (const float*)d_in[0];
  const float* wq = (const float*)d_in[1];
  const float* wk = (const float*)d_in[2];
  const float* wv = (const float*)d_in[3];
  const float* wo = (const float*)d_in[4];
  const int*  pos = (const int*)d_in[5];
  float* out = (float*)d_out;

  char* ws = (char*)d_ws;
  size_t off = 0;
  auto alloc = [&](size_t bytes)->char*{
    char* p = ws + off; off += (bytes + 255) & ~(size_t)255; return p;
  };
  u16* xb  = (u16*)alloc(8388608ull*2);   // x bf16 (4096x2048); reused as vt after gemm<0>
  u16* wcb = (u16*)alloc(6291456ull*2);   // Wq|Wk|Wv bf16 (3072x2048)
  u16* wob = (u16*)alloc(4194304ull*2);   // Wo bf16 (2048x2048)
  u16* qb  = (u16*)alloc(8388608ull*2);   // Q (4096x2048), SCALE_Q + rope applied
  u16* kb  = (u16*)alloc(2097152ull*2);   // K (4096x512), rope applied
  u16* vb  = (u16*)alloc(2097152ull*2);   // V (4096x512)
  u16* yb  = (u16*)alloc(8388608ull*2);   // attn out (4096x2048)
  float2* tab = (float2*)alloc((size_t)S_LEN*64*8);
  u16* vt = xb;                           // V^T [512][4096] — xb dead after gemm<0>

  convert_kernel<<<2048,256,0,stream>>>(x,wq,wk,wv,wo,xb,wcb,wob);
  rope_table_kernel<<<512,256,0,stream>>>(pos, tab);
  gemm128_kernel<0><<<dim3(24,32),256,0,stream>>>(xb, wcb, 2048, tab, qb, kb, vb, nullptr);
  transpose_v_kernel<<<512,256,0,stream>>>(vb, vt);
  attn_kernel<<<1024,256,0,stream>>>(qb, kb, vt, yb);
  gemm128_kernel<1><<<dim3(16,32),256,0,stream>>>(yb, wob, 2048, nullptr, nullptr,nullptr,nullptr, out);
}

// Round 8
// 314.238 us; speedup vs baseline: 1.2284x; 1.1116x over previous
//
#include <hip/hip_runtime.h>
#include <stdint.h>

typedef unsigned short u16;
typedef unsigned int   u32;
typedef __attribute__((ext_vector_type(8))) short short8;
typedef __attribute__((ext_vector_type(4))) float f32x4;

#define S_LEN 2048
#define NEMB  2048
#define NH    16
#define NKV   4
#define HD    128
#define BATCH 2
#define MROWS (BATCH*S_LEN)   // 4096

// 1/sqrt(128) * log2(e): scores land in log2 domain -> bare v_exp_f32 softmax
#define SCALE_Q 0.12751744f

__device__ __forceinline__ u16 f2bf(float f){
  u32 u = __float_as_uint(f);
  u += 0x7fffu + ((u>>16)&1u);
  return (u16)(u>>16);
}
__device__ __forceinline__ float bf2f(u16 h){
  return __uint_as_float(((u32)h)<<16);
}
__device__ __forceinline__ float exp2_fast(float x){
  float r;
  asm("v_exp_f32 %0, %1" : "=v"(r) : "v"(x));
  return r;
}

typedef __attribute__((address_space(1))) const void gc_void;
typedef __attribute__((address_space(3))) void lds_void;
__device__ __forceinline__ void load_lds16(const void* g, void* l){
  __builtin_amdgcn_global_load_lds((gc_void*)(uintptr_t)g,
      (lds_void*)(u32)(uintptr_t)l, 16, 0, 0);
}

// ---------------- convert f32 -> bf16 (x, Wq|Wk|Wv concat, Wo) ----------------
__global__ __launch_bounds__(256) void convert_kernel(
    const float* __restrict__ x, const float* __restrict__ wq,
    const float* __restrict__ wk, const float* __restrict__ wv,
    const float* __restrict__ wo,
    u16* __restrict__ xb, u16* __restrict__ wcb, u16* __restrict__ wob){
  const size_t NX=2097152, NWQ=1048576, NWK=262144, NWV=262144, NWO=1048576;
  const size_t total = NX+NWQ+NWK+NWV+NWO;   // in float4 chunks
  for (size_t i = (size_t)blockIdx.x*blockDim.x + threadIdx.x; i < total;
       i += (size_t)gridDim.x*blockDim.x){
    const float* src; u16* dst; size_t j = i;
    if (j < NX){ src=x; dst=xb; }
    else { j-=NX;
      if (j<NWQ){ src=wq; dst=wcb; }
      else { j-=NWQ;
        if (j<NWK){ src=wk; dst=wcb+4194304; }
        else { j-=NWK;
          if (j<NWV){ src=wv; dst=wcb+5242880; }
          else { j-=NWV; src=wo; dst=wob; } } } }
    float4 v = *(const float4*)(src + j*4);
    u32 lo = (u32)f2bf(v.x) | ((u32)f2bf(v.y)<<16);
    u32 hi = (u32)f2bf(v.z) | ((u32)f2bf(v.w)<<16);
    uint2 pk; pk.x = lo; pk.y = hi;
    *(uint2*)(dst + j*4) = pk;
  }
}

// ---------------- RoPE cos/sin table: tab[s*64+i] = {cos, sin} ----------------
__global__ __launch_bounds__(256) void rope_table_kernel(const int* __restrict__ pos,
                                                         float2* __restrict__ tab){
  int id = blockIdx.x*256 + threadIdx.x;
  if (id >= S_LEN*64) return;
  int s = id >> 6, i = id & 63;
  float p = (float)pos[s];
  float inv = __expf(-((float)(2*i)) * (1.0f/128.0f) * 9.210340371976184f);
  float f = p * inv;
  float sv, cv;
  sincosf(f, &sv, &cv);
  tab[id] = make_float2(cv, sv);
}

// ---------------- V transpose: vb [4096][512] -> vt [512][4096] ----------------
__global__ __launch_bounds__(256) void transpose_v_kernel(const u16* __restrict__ vb,
                                                          u16* __restrict__ vt){
  __shared__ u16 tl[64][72];
  int bx = blockIdx.x;
  int m0 = (bx & 63)*64;
  int d0 = (bx >> 6)*64;
  int tid = threadIdx.x;
  #pragma unroll
  for (int i=0;i<2;i++){
    int t16 = i*256 + tid;
    int sl = t16 >> 3, dc = t16 & 7;
    *(uint4*)&tl[sl][dc*8] = *(const uint4*)&vb[(size_t)(m0+sl)*512 + d0 + dc*8];
  }
  __syncthreads();
  #pragma unroll
  for (int i=0;i<2;i++){
    int t16 = i*256 + tid;
    int sch = t16 >> 6, dl = t16 & 63;
    union { uint4 v; u16 e[8]; } O;
    #pragma unroll
    for (int j=0;j<8;j++) O.e[j] = tl[sch*8+j][dl];
    *(uint4*)&vt[(size_t)(d0+dl)*4096 + m0 + sch*8] = O.v;
  }
}

// ---------------- 128x128 bf16 GEMM, B^T input ----------------
// EPI 0: QKV proj — RoPE fused in epilogue (Q scaled by SCALE_Q), scatter to q/k/v
// EPI 1: output proj — f32 to f_out
template<int EPI>
__global__ __launch_bounds__(256,2) void gemm128_kernel(
    const u16* __restrict__ A, const u16* __restrict__ B, int K,
    const float2* __restrict__ tab,
    u16* __restrict__ q_out, u16* __restrict__ k_out, u16* __restrict__ v_out,
    float* __restrict__ f_out){
  __shared__ u16 sA[2][128*32];
  __shared__ u16 sB[2][128*32];
  int tid = threadIdx.x;
  int wave = tid >> 6, lane = tid & 63;
  int lr = lane & 15, lc = lane >> 4;
  int wm = (wave>>1)*64, wn = (wave&1)*64;
  int bm = blockIdx.y*128, bn = blockIdx.x*128;
  const u16* Ag = A + (size_t)bm*K;
  const u16* Bg = B + (size_t)bn*K;

  auto stage = [&](int buf, int kt){
    const u16* Ak = Ag + kt*32;
    const u16* Bk = Bg + kt*32;
    #pragma unroll
    for (int rrd=0; rrd<2; ++rrd){
      int t16 = rrd*256 + tid;
      int row = t16 >> 2, ch = t16 & 3;
      u16* lb = &sA[buf][(size_t)(rrd*256 + (tid & 192))*8];
      load_lds16(Ak + (size_t)row*K + ch*8, lb);
    }
    #pragma unroll
    for (int rrd=0; rrd<2; ++rrd){
      int t16 = rrd*256 + tid;
      int row = t16 >> 2, ch = t16 & 3;
      u16* lb = &sB[buf][(size_t)(rrd*256 + (tid & 192))*8];
      load_lds16(Bk + (size_t)row*K + ch*8, lb);
    }
  };

  f32x4 acc[4][4];
  #pragma unroll
  for (int i=0;i<4;i++)
    #pragma unroll
    for (int j=0;j<4;j++) acc[i][j] = (f32x4)0.0f;

  stage(0,0);
  __syncthreads();
  int nk = K >> 5;
  int cur = 0;
  for (int kt=0; kt<nk; ++kt){
    if (kt+1 < nk) stage(cur^1, kt+1);
    short8 af[4], bfr[4];
    #pragma unroll
    for (int i=0;i<4;i++){
      af[i]  = *(const short8*)&sA[cur][(wm + i*16 + lr)*32 + lc*8];
      bfr[i] = *(const short8*)&sB[cur][(wn + i*16 + lr)*32 + lc*8];
    }
    __builtin_amdgcn_s_setprio(1);
    #pragma unroll
    for (int i=0;i<4;i++)
      #pragma unroll
      for (int j=0;j<4;j++)
        acc[i][j] = __builtin_amdgcn_mfma_f32_16x16x32_bf16(af[i], bfr[j], acc[i][j], 0,0,0);
    __builtin_amdgcn_s_setprio(0);
    __syncthreads();
    cur ^= 1;
  }

  #pragma unroll
  for (int i=0;i<4;i++){
    #pragma unroll
    for (int j=0;j<4;j++){
      #pragma unroll
      for (int r=0;r<4;r++){
        int m = bm + wm + i*16 + lc*4 + r;
        int n = bn + wn + j*16 + lr;
        float v = acc[i][j][r];
        if (EPI == 0){
          // RoPE: partner value (d ^ 1) lives in lane^1 (lr parity)
          float p = __shfl_xor(v, 1);
          if (n < 2048){
            float2 cs = tab[((m & (S_LEN-1))<<6) + ((n & 127)>>1)];
            float o = (n & 1) ? (v*cs.x + p*cs.y) : (v*cs.x - p*cs.y);
            q_out[(size_t)m*2048 + n] = f2bf(o * SCALE_Q);
          } else if (n < 2560){
            int d = n - 2048;           // d in [0,512): head dim = d&127
            float2 cs = tab[((m & (S_LEN-1))<<6) + ((d & 127)>>1)];
            float o = (n & 1) ? (v*cs.x + p*cs.y) : (v*cs.x - p*cs.y);
            k_out[(size_t)m*512 + d] = f2bf(o);
          } else {
            v_out[(size_t)m*512 + (n-2560)] = f2bf(v);
          }
        } else {
          f_out[(size_t)m*2048 + n] = v;
        }
      }
    }
  }
}

// ---------------- flash attention: paired q-tiles {31-j, j} = 33 tiles/block ----------------
// grid 512: bid&7 = (b,hk) [XCD-sticky]; each block perfectly load-balanced
__global__ __launch_bounds__(256,2) void attn_kernel(
    const u16* __restrict__ Q, const u16* __restrict__ Kb,
    const u16* __restrict__ Vt, u16* __restrict__ Y){
  __shared__ u16 sK[2][64*128];    // [kv][128d], XOR-swizzled 16B chunks
  __shared__ u16 sVt[2][128*64];   // [d][64kv], XOR-swizzled 16B chunks
  __shared__ u16 sP[4][16*64];     // per-wave P, XOR-swizzled

  int tid = threadIdx.x, wave = tid>>6, lane = tid&63;
  int lr = lane&15, lc = lane>>4;

  int bid = blockIdx.x;
  int kvg  = bid & 7;          // (b,hk)
  int rest = bid >> 3;         // 0..63
  int pj   = rest & 15;        // pair index: qt in {31-pj, pj}
  int hsub = rest >> 4;        // 0..3
  int b  = kvg >> 2;
  int hk = kvg & 3;
  int h  = hk*4 + hsub;

  const u16* Kg = Kb + (size_t)(b*S_LEN)*512 + hk*HD;
  const u16* Vg = Vt + (size_t)(hk*HD)*4096 + b*S_LEN;

  auto stage = [&](int buf, int kv0){
    #pragma unroll
    for (int i=0;i<4;i++){
      int t16 = i*256 + tid;
      int row = t16 >> 4, c = t16 & 15;
      int cgl = c ^ (row & 7);
      load_lds16(Kg + (size_t)(kv0+row)*512 + cgl*8,
                 &sK[buf][(size_t)(i*256 + (tid & 192))*8]);
    }
    #pragma unroll
    for (int i=0;i<4;i++){
      int t16 = i*256 + tid;
      int d = t16 >> 3, c = t16 & 7;
      int cgl = c ^ (d & 7);
      load_lds16(Vg + (size_t)d*4096 + kv0 + cgl*8,
                 &sVt[buf][(size_t)(i*256 + (tid & 192))*8]);
    }
  };

  char* spb = (char*)sP[wave];

  #pragma unroll 1
  for (int pass=0; pass<2; ++pass){
    int qt  = pass ? pj : (31 - pj);   // long tile first
    int q0  = qt*64;
    int qrb = q0 + wave*16;
    const u16* Qg = Q + (size_t)(b*S_LEN + qrb)*NEMB + h*HD;

    short8 qf[4];
    #pragma unroll
    for (int c=0;c<4;c++)
      qf[c] = *(const short8*)&Qg[(size_t)lr*NEMB + c*32 + lc*8];

    float m_run[4], l_run[4];
    #pragma unroll
    for (int r=0;r<4;r++){ m_run[r]=-1e30f; l_run[r]=0.0f; }
    f32x4 o[8];
    #pragma unroll
    for (int i=0;i<8;i++) o[i]=(f32x4)0.0f;

    int nt = qt + 1;
    stage(0,0);
    __syncthreads();
    int cur=0;
    for (int t=0;t<nt;++t){
      int kv0 = t*64;
      if (t+1<nt) stage(cur^1,(t+1)*64);

      // ---- QK^T (scores in log2 units via SCALE_Q on Q) ----
      f32x4 sc[4];
      #pragma unroll
      for (int c2=0;c2<4;c2++) sc[c2]=(f32x4)0.0f;
      const char* skb = (const char*)sK[cur];
      __builtin_amdgcn_s_setprio(1);
      #pragma unroll
      for (int c2=0;c2<4;c2++){
        int rr = c2*16 + lr;
        int xo = (rr&7)<<4;
        #pragma unroll
        for (int c=0;c<4;c++){
          int byteoff = (rr*256 + c*64 + lc*16) ^ xo;
          short8 kf = *(const short8*)(skb + byteoff);
          sc[c2] = __builtin_amdgcn_mfma_f32_16x16x32_bf16(qf[c], kf, sc[c2], 0,0,0);
        }
      }
      __builtin_amdgcn_s_setprio(0);

      if (t == nt-1){          // diagonal tile: causal mask (all waves)
        #pragma unroll
        for (int c2=0;c2<4;c2++){
          int kvgl = kv0 + c2*16 + lr;
          #pragma unroll
          for (int r=0;r<4;r++){
            int qg = qrb + lc*4 + r;
            if (kvgl > qg) sc[c2][r] = -1e30f;
          }
        }
      }

      // ---- defer-max online softmax (T13) ----
      float lmax[4];
      bool need = false;
      #pragma unroll
      for (int r=0;r<4;r++){
        lmax[r] = fmaxf(fmaxf(sc[0][r],sc[1][r]), fmaxf(sc[2][r],sc[3][r]));
        need = need || (lmax[r] > m_run[r] + 8.0f);
      }
      if (__any(need)){
        float fac[4];
        #pragma unroll
        for (int r=0;r<4;r++){
          float mm = lmax[r];
          mm = fmaxf(mm, __shfl_xor(mm,1));
          mm = fmaxf(mm, __shfl_xor(mm,2));
          mm = fmaxf(mm, __shfl_xor(mm,4));
          mm = fmaxf(mm, __shfl_xor(mm,8));
          float mn = fmaxf(m_run[r], mm);
          fac[r] = exp2_fast(m_run[r]-mn);
          m_run[r] = mn;
          l_run[r] *= fac[r];
        }
        #pragma unroll
        for (int i=0;i<8;i++)
          #pragma unroll
          for (int r=0;r<4;r++) o[i][r] *= fac[r];
      }
      #pragma unroll
      for (int r=0;r<4;r++){
        float p0 = exp2_fast(sc[0][r]-m_run[r]);
        float p1 = exp2_fast(sc[1][r]-m_run[r]);
        float p2 = exp2_fast(sc[2][r]-m_run[r]);
        float p3 = exp2_fast(sc[3][r]-m_run[r]);
        sc[0][r]=p0; sc[1][r]=p1; sc[2][r]=p2; sc[3][r]=p3;
        float ss = (p0+p1)+(p2+p3);
        ss += __shfl_xor(ss,1); ss += __shfl_xor(ss,2);
        ss += __shfl_xor(ss,4); ss += __shfl_xor(ss,8);
        l_run[r] += ss;
      }

      // ---- P: C-layout -> swizzled LDS -> A-frag ----
      #pragma unroll
      for (int c2=0;c2<4;c2++){
        #pragma unroll
        for (int r=0;r<4;r++){
          int row = lc*4+r;
          int byteoff = (row*128 + (c2*16+lr)*2) ^ ((row&7)<<4);
          *(u16*)(spb + byteoff) = f2bf(sc[c2][r]);
        }
      }
      short8 pa[2];
      {
        int xop = (lr&7)<<4;
        pa[0] = *(const short8*)(spb + ((lr*128 + lc*16) ^ xop));
        pa[1] = *(const short8*)(spb + ((lr*128 + 64 + lc*16) ^ xop));
      }

      // ---- PV ----
      const char* svb = (const char*)sVt[cur];
      __builtin_amdgcn_s_setprio(1);
      #pragma unroll
      for (int n=0;n<8;n++){
        int d = n*16+lr;
        int xo = (d&7)<<4;
        #pragma unroll
        for (int ks=0;ks<2;ks++){
          int byteoff = (d*128 + ks*64 + lc*16) ^ xo;
          short8 vf = *(const short8*)(svb + byteoff);
          o[n] = __builtin_amdgcn_mfma_f32_16x16x32_bf16(pa[ks], vf, o[n], 0,0,0);
        }
      }
      __builtin_amdgcn_s_setprio(0);

      __syncthreads();
      cur ^= 1;
    }

    u16* Yg = Y + (size_t)(b*S_LEN + qrb)*NEMB + h*HD;
    #pragma unroll
    for (int n=0;n<8;n++){
      #pragma unroll
      for (int r=0;r<4;r++){
        float v = o[n][r] / l_run[r];
        Yg[(size_t)(lc*4+r)*NEMB + n*16 + lr] = f2bf(v);
      }
    }
    __syncthreads();   // buffers idle before next pass re-stages
  }
}

// ---------------- launch ----------------
extern "C" void kernel_launch(void* const* d_in, const int* in_sizes, int n_in,
                              void* d_out, int out_size, void* d_ws, size_t ws_size,
                              hipStream_t stream){
  const float* x  = (const float*)d_in[0];
  const float* wq = (const float*)d_in[1];
  const float* wk = (const float*)d_in[2];
  const float* wv = (const float*)d_in[3];
  const float* wo = (const float*)d_in[4];
  const int*  pos = (const int*)d_in[5];
  float* out = (float*)d_out;

  char* ws = (char*)d_ws;
  size_t off = 0;
  auto alloc = [&](size_t bytes)->char*{
    char* p = ws + off; off += (bytes + 255) & ~(size_t)255; return p;
  };
  u16* xb  = (u16*)alloc(8388608ull*2);   // x bf16 (4096x2048); reused as vt after gemm<0>
  u16* wcb = (u16*)alloc(6291456ull*2);   // Wq|Wk|Wv bf16 (3072x2048)
  u16* wob = (u16*)alloc(4194304ull*2);   // Wo bf16 (2048x2048)
  u16* qb  = (u16*)alloc(8388608ull*2);   // Q (4096x2048), SCALE_Q + rope applied
  u16* kb  = (u16*)alloc(2097152ull*2);   // K (4096x512), rope applied
  u16* vb  = (u16*)alloc(2097152ull*2);   // V (4096x512)
  u16* yb  = (u16*)alloc(8388608ull*2);   // attn out (4096x2048)
  float2* tab = (float2*)alloc((size_t)S_LEN*64*8);
  u16* vt = xb;                           // V^T [512][4096] — xb dead after gemm<0>

  convert_kernel<<<2048,256,0,stream>>>(x,wq,wk,wv,wo,xb,wcb,wob);
  rope_table_kernel<<<512,256,0,stream>>>(pos, tab);
  gemm128_kernel<0><<<dim3(24,32),256,0,stream>>>(xb, wcb, 2048, tab, qb, kb, vb, nullptr);
  transpose_v_kernel<<<512,256,0,stream>>>(vb, vt);
  attn_kernel<<<512,256,0,stream>>>(qb, kb, vt, yb);
  gemm128_kernel<1><<<dim3(16,32),256,0,stream>>>(yb, wob, 2048, nullptr, nullptr,nullptr,nullptr, out);
}

// Round 9
// 292.791 us; speedup vs baseline: 1.3184x; 1.0732x over previous
//
#include <hip/hip_runtime.h>
#include <stdint.h>

typedef unsigned short u16;
typedef unsigned int   u32;
typedef __attribute__((ext_vector_type(8))) short short8;
typedef __attribute__((ext_vector_type(4))) float f32x4;

#define S_LEN 2048
#define NEMB  2048
#define NH    16
#define NKV   4
#define HD    128
#define BATCH 2
#define MROWS (BATCH*S_LEN)   // 4096

// 1/sqrt(128) * log2(e): scores land in log2 domain -> bare v_exp_f32 softmax
#define SCALE_Q 0.12751744f

__device__ __forceinline__ u16 f2bf(float f){
  u32 u = __float_as_uint(f);
  u += 0x7fffu + ((u>>16)&1u);
  return (u16)(u>>16);
}
__device__ __forceinline__ u16 f2bf_t(float f){   // truncating (internal P only)
  return (u16)(__float_as_uint(f)>>16);
}
__device__ __forceinline__ float bf2f(u16 h){
  return __uint_as_float(((u32)h)<<16);
}
__device__ __forceinline__ float exp2_fast(float x){
  float r;
  asm("v_exp_f32 %0, %1" : "=v"(r) : "v"(x));
  return r;
}

typedef __attribute__((address_space(1))) const void gc_void;
typedef __attribute__((address_space(3))) void lds_void;
__device__ __forceinline__ void load_lds16(const void* g, void* l){
  __builtin_amdgcn_global_load_lds((gc_void*)(uintptr_t)g,
      (lds_void*)(u32)(uintptr_t)l, 16, 0, 0);
}

// ---------------- convert f32 -> bf16 + RoPE table (fused) ----------------
__global__ __launch_bounds__(256) void convert_kernel(
    const float* __restrict__ x, const float* __restrict__ wq,
    const float* __restrict__ wk, const float* __restrict__ wv,
    const float* __restrict__ wo,
    u16* __restrict__ xb, u16* __restrict__ wcb, u16* __restrict__ wob,
    const int* __restrict__ pos, float2* __restrict__ tab){
  const size_t NX=2097152, NWQ=1048576, NWK=262144, NWV=262144, NWO=1048576;
  const size_t total = NX+NWQ+NWK+NWV+NWO;   // in float4 chunks
  for (size_t i = (size_t)blockIdx.x*blockDim.x + threadIdx.x; i < total;
       i += (size_t)gridDim.x*blockDim.x){
    const float* src; u16* dst; size_t j = i;
    if (j < NX){ src=x; dst=xb; }
    else { j-=NX;
      if (j<NWQ){ src=wq; dst=wcb; }
      else { j-=NWQ;
        if (j<NWK){ src=wk; dst=wcb+4194304; }
        else { j-=NWK;
          if (j<NWV){ src=wv; dst=wcb+5242880; }
          else { j-=NWV; src=wo; dst=wob; } } } }
    float4 v = *(const float4*)(src + j*4);
    u32 lo = (u32)f2bf(v.x) | ((u32)f2bf(v.y)<<16);
    u32 hi = (u32)f2bf(v.z) | ((u32)f2bf(v.w)<<16);
    uint2 pk; pk.x = lo; pk.y = hi;
    *(uint2*)(dst + j*4) = pk;
  }
  // RoPE table: 131072 entries
  for (int id = blockIdx.x*blockDim.x + threadIdx.x; id < S_LEN*64;
       id += gridDim.x*blockDim.x){
    int s = id >> 6, i = id & 63;
    float p = (float)pos[s];
    float inv = __expf(-((float)(2*i)) * (1.0f/128.0f) * 9.210340371976184f);
    float f = p * inv;
    float sv, cv;
    sincosf(f, &sv, &cv);
    tab[id] = make_float2(cv, sv);
  }
}

// ---------------- V transpose: vb [4096][512] -> vt [512][4096] ----------------
__global__ __launch_bounds__(256) void transpose_v_kernel(const u16* __restrict__ vb,
                                                          u16* __restrict__ vt){
  __shared__ u16 tl[64][72];
  int bx = blockIdx.x;
  int m0 = (bx & 63)*64;
  int d0 = (bx >> 6)*64;
  int tid = threadIdx.x;
  #pragma unroll
  for (int i=0;i<2;i++){
    int t16 = i*256 + tid;
    int sl = t16 >> 3, dc = t16 & 7;
    *(uint4*)&tl[sl][dc*8] = *(const uint4*)&vb[(size_t)(m0+sl)*512 + d0 + dc*8];
  }
  __syncthreads();
  #pragma unroll
  for (int i=0;i<2;i++){
    int t16 = i*256 + tid;
    int sch = t16 >> 6, dl = t16 & 63;
    union { uint4 v; u16 e[8]; } O;
    #pragma unroll
    for (int j=0;j<8;j++) O.e[j] = tl[sch*8+j][dl];
    *(uint4*)&vt[(size_t)(d0+dl)*4096 + m0 + sch*8] = O.v;
  }
}

// ---------------- 128x128 bf16 GEMM, B^T input ----------------
// EPI 0: QKV proj — RoPE fused in epilogue (Q scaled by SCALE_Q), scatter to q/k/v
// EPI 1: output proj — f32 to f_out
// __launch_bounds__(256,3): cap VGPR<=168 -> 3 blocks/CU (m97 precedent: 164 VGPR)
template<int EPI>
__global__ __launch_bounds__(256,3) void gemm128_kernel(
    const u16* __restrict__ A, const u16* __restrict__ B, int K,
    const float2* __restrict__ tab,
    u16* __restrict__ q_out, u16* __restrict__ k_out, u16* __restrict__ v_out,
    float* __restrict__ f_out){
  __shared__ u16 sA[2][128*32];
  __shared__ u16 sB[2][128*32];
  int tid = threadIdx.x;
  int wave = tid >> 6, lane = tid & 63;
  int lr = lane & 15, lc = lane >> 4;
  int wm = (wave>>1)*64, wn = (wave&1)*64;

  // T1: bijective XCD swizzle (nwg % 8 == 0 at both call sites)
  int nwgx = gridDim.x;
  int nwg  = nwgx * gridDim.y;
  int wg   = blockIdx.y*nwgx + blockIdx.x;
  wg = (wg & 7)*(nwg >> 3) + (wg >> 3);
  int bm = (wg / nwgx)*128, bn = (wg % nwgx)*128;

  const u16* Ag = A + (size_t)bm*K;
  const u16* Bg = B + (size_t)bn*K;

  auto stage = [&](int buf, int kt){
    const u16* Ak = Ag + kt*32;
    const u16* Bk = Bg + kt*32;
    #pragma unroll
    for (int rrd=0; rrd<2; ++rrd){
      int t16 = rrd*256 + tid;
      int row = t16 >> 2, ch = t16 & 3;
      u16* lb = &sA[buf][(size_t)(rrd*256 + (tid & 192))*8];
      load_lds16(Ak + (size_t)row*K + ch*8, lb);
    }
    #pragma unroll
    for (int rrd=0; rrd<2; ++rrd){
      int t16 = rrd*256 + tid;
      int row = t16 >> 2, ch = t16 & 3;
      u16* lb = &sB[buf][(size_t)(rrd*256 + (tid & 192))*8];
      load_lds16(Bk + (size_t)row*K + ch*8, lb);
    }
  };

  f32x4 acc[4][4];
  #pragma unroll
  for (int i=0;i<4;i++)
    #pragma unroll
    for (int j=0;j<4;j++) acc[i][j] = (f32x4)0.0f;

  stage(0,0);
  __syncthreads();
  int nk = K >> 5;
  int cur = 0;
  for (int kt=0; kt<nk; ++kt){
    if (kt+1 < nk) stage(cur^1, kt+1);
    short8 af[4], bfr[4];
    #pragma unroll
    for (int i=0;i<4;i++){
      af[i]  = *(const short8*)&sA[cur][(wm + i*16 + lr)*32 + lc*8];
      bfr[i] = *(const short8*)&sB[cur][(wn + i*16 + lr)*32 + lc*8];
    }
    __builtin_amdgcn_s_setprio(1);
    #pragma unroll
    for (int i=0;i<4;i++)
      #pragma unroll
      for (int j=0;j<4;j++)
        acc[i][j] = __builtin_amdgcn_mfma_f32_16x16x32_bf16(af[i], bfr[j], acc[i][j], 0,0,0);
    __builtin_amdgcn_s_setprio(0);
    __syncthreads();
    cur ^= 1;
  }

  #pragma unroll
  for (int i=0;i<4;i++){
    #pragma unroll
    for (int j=0;j<4;j++){
      #pragma unroll
      for (int r=0;r<4;r++){
        int m = bm + wm + i*16 + lc*4 + r;
        int n = bn + wn + j*16 + lr;
        float v = acc[i][j][r];
        if (EPI == 0){
          // RoPE: partner value (d ^ 1) lives in lane^1 (lr parity)
          float p = __shfl_xor(v, 1);
          if (n < 2048){
            float2 cs = tab[((m & (S_LEN-1))<<6) + ((n & 127)>>1)];
            float o = (n & 1) ? (v*cs.x + p*cs.y) : (v*cs.x - p*cs.y);
            q_out[(size_t)m*2048 + n] = f2bf(o * SCALE_Q);
          } else if (n < 2560){
            int d = n - 2048;           // d in [0,512): head dim = d&127
            float2 cs = tab[((m & (S_LEN-1))<<6) + ((d & 127)>>1)];
            float o = (n & 1) ? (v*cs.x + p*cs.y) : (v*cs.x - p*cs.y);
            k_out[(size_t)m*512 + d] = f2bf(o);
          } else {
            v_out[(size_t)m*512 + (n-2560)] = f2bf(v);
          }
        } else {
          f_out[(size_t)m*2048 + n] = v;
        }
      }
    }
  }
}

// ---------------- flash attention: paired q-tiles {31-j, j} = 33 tiles/block ----------------
// grid 512: bid&7 = (b,hk) [XCD-sticky]; deferred-l softmax, rcp epilogue
__global__ __launch_bounds__(256,2) void attn_kernel(
    const u16* __restrict__ Q, const u16* __restrict__ Kb,
    const u16* __restrict__ Vt, u16* __restrict__ Y){
  __shared__ u16 sK[2][64*128];    // [kv][128d], XOR-swizzled 16B chunks
  __shared__ u16 sVt[2][128*64];   // [d][64kv], XOR-swizzled 16B chunks
  __shared__ u16 sP[4][16*64];     // per-wave P, XOR-swizzled

  int tid = threadIdx.x, wave = tid>>6, lane = tid&63;
  int lr = lane&15, lc = lane>>4;

  int bid = blockIdx.x;
  int kvg  = bid & 7;          // (b,hk)
  int rest = bid >> 3;         // 0..63
  int pj   = rest & 15;        // pair index: qt in {31-pj, pj}
  int hsub = rest >> 4;        // 0..3
  int b  = kvg >> 2;
  int hk = kvg & 3;
  int h  = hk*4 + hsub;

  const u16* Kg = Kb + (size_t)(b*S_LEN)*512 + hk*HD;
  const u16* Vg = Vt + (size_t)(hk*HD)*4096 + b*S_LEN;

  auto stage = [&](int buf, int kv0){
    #pragma unroll
    for (int i=0;i<4;i++){
      int t16 = i*256 + tid;
      int row = t16 >> 4, c = t16 & 15;
      int cgl = c ^ (row & 7);
      load_lds16(Kg + (size_t)(kv0+row)*512 + cgl*8,
                 &sK[buf][(size_t)(i*256 + (tid & 192))*8]);
    }
    #pragma unroll
    for (int i=0;i<4;i++){
      int t16 = i*256 + tid;
      int d = t16 >> 3, c = t16 & 7;
      int cgl = c ^ (d & 7);
      load_lds16(Vg + (size_t)d*4096 + kv0 + cgl*8,
                 &sVt[buf][(size_t)(i*256 + (tid & 192))*8]);
    }
  };

  char* spb = (char*)sP[wave];

  #pragma unroll 1
  for (int pass=0; pass<2; ++pass){
    int qt  = pass ? pj : (31 - pj);   // long tile first
    int q0  = qt*64;
    int qrb = q0 + wave*16;
    const u16* Qg = Q + (size_t)(b*S_LEN + qrb)*NEMB + h*HD;

    short8 qf[4];
    #pragma unroll
    for (int c=0;c<4;c++)
      qf[c] = *(const short8*)&Qg[(size_t)lr*NEMB + c*32 + lc*8];

    float m_run[4], l_run[4];   // l_run: PER-LANE partial (reduced in epilogue)
    #pragma unroll
    for (int r=0;r<4;r++){ m_run[r]=-1e30f; l_run[r]=0.0f; }
    f32x4 o[8];
    #pragma unroll
    for (int i=0;i<8;i++) o[i]=(f32x4)0.0f;

    int nt = qt + 1;
    stage(0,0);
    __syncthreads();
    int cur=0;
    for (int t=0;t<nt;++t){
      int kv0 = t*64;
      if (t+1<nt) stage(cur^1,(t+1)*64);

      // ---- QK^T (scores in log2 units via SCALE_Q on Q) ----
      f32x4 sc[4];
      #pragma unroll
      for (int c2=0;c2<4;c2++) sc[c2]=(f32x4)0.0f;
      const char* skb = (const char*)sK[cur];
      __builtin_amdgcn_s_setprio(1);
      #pragma unroll
      for (int c2=0;c2<4;c2++){
        int rr = c2*16 + lr;
        int xo = (rr&7)<<4;
        #pragma unroll
        for (int c=0;c<4;c++){
          int byteoff = (rr*256 + c*64 + lc*16) ^ xo;
          short8 kf = *(const short8*)(skb + byteoff);
          sc[c2] = __builtin_amdgcn_mfma_f32_16x16x32_bf16(qf[c], kf, sc[c2], 0,0,0);
        }
      }
      __builtin_amdgcn_s_setprio(0);

      if (t == nt-1){          // diagonal tile: causal mask (all waves)
        #pragma unroll
        for (int c2=0;c2<4;c2++){
          int kvgl = kv0 + c2*16 + lr;
          #pragma unroll
          for (int r=0;r<4;r++){
            int qg = qrb + lc*4 + r;
            if (kvgl > qg) sc[c2][r] = -1e30f;
          }
        }
      }

      // ---- defer-max online softmax (T13) ----
      float lmax[4];
      bool need = false;
      #pragma unroll
      for (int r=0;r<4;r++){
        lmax[r] = fmaxf(fmaxf(sc[0][r],sc[1][r]), fmaxf(sc[2][r],sc[3][r]));
        need = need || (lmax[r] > m_run[r] + 8.0f);
      }
      if (__any(need)){
        float fac[4];
        #pragma unroll
        for (int r=0;r<4;r++){
          float mm = lmax[r];
          mm = fmaxf(mm, __shfl_xor(mm,1));
          mm = fmaxf(mm, __shfl_xor(mm,2));
          mm = fmaxf(mm, __shfl_xor(mm,4));
          mm = fmaxf(mm, __shfl_xor(mm,8));
          float mn = fmaxf(m_run[r], mm);
          fac[r] = exp2_fast(m_run[r]-mn);   // wave-uniform within row group
          m_run[r] = mn;
          l_run[r] *= fac[r];                // per-lane partial scales uniformly
        }
        #pragma unroll
        for (int i=0;i<8;i++)
          #pragma unroll
          for (int r=0;r<4;r++) o[i][r] *= fac[r];
      }
      #pragma unroll
      for (int r=0;r<4;r++){
        float p0 = exp2_fast(sc[0][r]-m_run[r]);
        float p1 = exp2_fast(sc[1][r]-m_run[r]);
        float p2 = exp2_fast(sc[2][r]-m_run[r]);
        float p3 = exp2_fast(sc[3][r]-m_run[r]);
        sc[0][r]=p0; sc[1][r]=p1; sc[2][r]=p2; sc[3][r]=p3;
        l_run[r] += (p0+p1)+(p2+p3);         // no per-tile shfl reduce
      }

      // ---- P: C-layout -> swizzled LDS -> A-frag (truncating bf16) ----
      #pragma unroll
      for (int c2=0;c2<4;c2++){
        #pragma unroll
        for (int r=0;r<4;r++){
          int row = lc*4+r;
          int byteoff = (row*128 + (c2*16+lr)*2) ^ ((row&7)<<4);
          *(u16*)(spb + byteoff) = f2bf_t(sc[c2][r]);
        }
      }
      short8 pa[2];
      {
        int xop = (lr&7)<<4;
        pa[0] = *(const short8*)(spb + ((lr*128 + lc*16) ^ xop));
        pa[1] = *(const short8*)(spb + ((lr*128 + 64 + lc*16) ^ xop));
      }

      // ---- PV ----
      const char* svb = (const char*)sVt[cur];
      __builtin_amdgcn_s_setprio(1);
      #pragma unroll
      for (int n=0;n<8;n++){
        int d = n*16+lr;
        int xo = (d&7)<<4;
        #pragma unroll
        for (int ks=0;ks<2;ks++){
          int byteoff = (d*128 + ks*64 + lc*16) ^ xo;
          short8 vf = *(const short8*)(svb + byteoff);
          o[n] = __builtin_amdgcn_mfma_f32_16x16x32_bf16(pa[ks], vf, o[n], 0,0,0);
        }
      }
      __builtin_amdgcn_s_setprio(0);

      __syncthreads();
      cur ^= 1;
    }

    // ---- epilogue: reduce l across the 16 kv lanes, rcp, write ----
    float inv[4];
    #pragma unroll
    for (int r=0;r<4;r++){
      float s = l_run[r];
      s += __shfl_xor(s,1); s += __shfl_xor(s,2);
      s += __shfl_xor(s,4); s += __shfl_xor(s,8);
      inv[r] = __builtin_amdgcn_rcpf(s);
    }
    u16* Yg = Y + (size_t)(b*S_LEN + qrb)*NEMB + h*HD;
    #pragma unroll
    for (int n=0;n<8;n++){
      #pragma unroll
      for (int r=0;r<4;r++){
        float v = o[n][r] * inv[r];
        Yg[(size_t)(lc*4+r)*NEMB + n*16 + lr] = f2bf(v);
      }
    }
    __syncthreads();   // buffers idle before next pass re-stages
  }
}

// ---------------- launch ----------------
extern "C" void kernel_launch(void* const* d_in, const int* in_sizes, int n_in,
                              void* d_out, int out_size, void* d_ws, size_t ws_size,
                              hipStream_t stream){
  const float* x  = (const float*)d_in[0];
  const float* wq = (const float*)d_in[1];
  const float* wk = (const float*)d_in[2];
  const float* wv = (const float*)d_in[3];
  const float* wo = (const float*)d_in[4];
  const int*  pos = (const int*)d_in[5];
  float* out = (float*)d_out;

  char* ws = (char*)d_ws;
  size_t off = 0;
  auto alloc = [&](size_t bytes)->char*{
    char* p = ws + off; off += (bytes + 255) & ~(size_t)255; return p;
  };
  u16* xb  = (u16*)alloc(8388608ull*2);   // x bf16 (4096x2048); reused as vt after gemm<0>
  u16* wcb = (u16*)alloc(6291456ull*2);   // Wq|Wk|Wv bf16 (3072x2048)
  u16* wob = (u16*)alloc(4194304ull*2);   // Wo bf16 (2048x2048)
  u16* qb  = (u16*)alloc(8388608ull*2);   // Q (4096x2048), SCALE_Q + rope applied
  u16* kb  = (u16*)alloc(2097152ull*2);   // K (4096x512), rope applied
  u16* vb  = (u16*)alloc(2097152ull*2);   // V (4096x512)
  u16* yb  = (u16*)alloc(8388608ull*2);   // attn out (4096x2048)
  float2* tab = (float2*)alloc((size_t)S_LEN*64*8);
  u16* vt = xb;                           // V^T [512][4096] — xb dead after gemm<0>

  convert_kernel<<<2048,256,0,stream>>>(x,wq,wk,wv,wo,xb,wcb,wob,pos,tab);
  gemm128_kernel<0><<<dim3(24,32),256,0,stream>>>(xb, wcb, 2048, tab, qb, kb, vb, nullptr);
  transpose_v_kernel<<<512,256,0,stream>>>(vb, vt);
  attn_kernel<<<512,256,0,stream>>>(qb, kb, vt, yb);
  gemm128_kernel<1><<<dim3(16,32),256,0,stream>>>(yb, wob, 2048, nullptr, nullptr,nullptr,nullptr, out);
}